// Round 2
// baseline (2612.354 us; speedup 1.0000x reference)
//
#include <hip/hip_runtime.h>

// SkeletonConv: out[b,o,h,w] = sum_{c,k} W[o,c,k] * x[b,c, h+(k-1)*step, w+(k-1)*dil]
// B=64, C_in=C_out=16, K=3, H=W=256, fp32.
// R2: o-split x2 (8 outs/thread, 32 acc VGPRs), explicit next-c prefetch,
//     launch_bounds(256,8) to force <=64 VGPR / 8 waves/SIMD, NT stores.

constexpr int CIN = 16, COUT = 16, KK = 3, H = 256, W = 256;
constexpr int WT  = 4;            // w-elements per thread (float4)
constexpr int TPR = W / WT;       // 64 threads = one wave per (b,h,half) row
constexpr int OSPLIT = 2, OPT = COUT / OSPLIT;   // 8 output channels per thread

typedef float f4 __attribute__((ext_vector_type(4)));

__global__ __launch_bounds__(256, 8)
void skel_conv_kernel(const float* __restrict__ x, const float* __restrict__ wgt,
                      const int* __restrict__ dil_p, const int* __restrict__ step_p,
                      float* __restrict__ out, int B)
{
    const int dil  = dil_p[0];
    const int step = step_p[0];

    const int tid  = blockIdx.x * blockDim.x + threadIdx.x;
    const int lane = tid & (TPR - 1);            // lane-in-wave; wave spans a row
    int idx = tid / TPR;                         // (b, h, half)
    const int half = idx & (OSPLIT - 1);         // adjacent waves share the x row
    idx >>= 1;
    const int h = idx & (H - 1);
    const int b = idx >> 8;
    if (b >= B) return;
    const int w0    = lane * WT;
    const int obase = half * OPT;

    float acc[OPT][WT];
    #pragma unroll
    for (int o = 0; o < OPT; ++o)
        #pragma unroll
        for (int j = 0; j < WT; ++j) acc[o][j] = 0.f;

    const size_t cs = (size_t)H * W;
    const float* xr = x + (size_t)b * CIN * cs + (size_t)h * W + w0;

    if (dil == 1 && step == 0) {
        // Fast path: horizontal 3-tap conv, depth-1 software pipeline over c.
        f4 v = *(const f4*)xr;                   // c = 0
        #pragma unroll
        for (int c = 0; c < CIN; ++c) {
            f4 vn = {0.f, 0.f, 0.f, 0.f};
            if (c + 1 < CIN) vn = *(const f4*)(xr + (size_t)(c + 1) * cs);  // prefetch
            float left  = __shfl_up(v.w, 1);     // x[w0-1]
            float right = __shfl_down(v.x, 1);   // x[w0+4]
            if (lane == 0)       left  = 0.f;    // zero padding
            if (lane == TPR - 1) right = 0.f;

            #pragma unroll
            for (int oo = 0; oo < OPT; ++oo) {
                const float* wp = wgt + ((size_t)(obase + oo) * CIN + c) * KK;
                const float a0 = wp[0], a1 = wp[1], a2 = wp[2];   // uniform -> s_load
                acc[oo][0] += a0 * left + a1 * v.x + a2 * v.y;
                acc[oo][1] += a0 * v.x  + a1 * v.y + a2 * v.z;
                acc[oo][2] += a0 * v.y  + a1 * v.z + a2 * v.w;
                acc[oo][3] += a0 * v.z  + a1 * v.w + a2 * right;
            }
            v = vn;
        }
    } else {
        // Generic path: clamped loads + select (never faults, any dil/step).
        for (int c = 0; c < CIN; ++c) {
            const float* xc = x + (size_t)b * CIN * cs + (size_t)c * cs;
            #pragma unroll
            for (int k = 0; k < KK; ++k) {
                const int off = k - KK / 2;
                const int hh  = h + off * step;
                const bool rowok = (hh >= 0) && (hh < H);
                const int hcl = hh < 0 ? 0 : (hh > H - 1 ? H - 1 : hh);
                float t[WT];
                #pragma unroll
                for (int j = 0; j < WT; ++j) {
                    const int ww  = w0 + j + off * dil;
                    const bool ok = rowok && (ww >= 0) && (ww < W);
                    const int wcl = ww < 0 ? 0 : (ww > W - 1 ? W - 1 : ww);
                    const float vv = xc[(size_t)hcl * W + wcl];
                    t[j] = ok ? vv : 0.f;
                }
                #pragma unroll
                for (int oo = 0; oo < OPT; ++oo) {
                    const float wk = wgt[((size_t)(obase + oo) * CIN + c) * KK + k];
                    #pragma unroll
                    for (int j = 0; j < WT; ++j)
                        acc[oo][j] += wk * t[j];
                }
            }
        }
    }

    float* orow = out + ((size_t)b * COUT + obase) * cs + (size_t)h * W + w0;
    #pragma unroll
    for (int oo = 0; oo < OPT; ++oo) {
        f4 r = {acc[oo][0], acc[oo][1], acc[oo][2], acc[oo][3]};
        __builtin_nontemporal_store(r, (f4*)(orow + (size_t)oo * cs));  // don't evict x from L3
    }
}

extern "C" void kernel_launch(void* const* d_in, const int* in_sizes, int n_in,
                              void* d_out, int out_size, void* d_ws, size_t ws_size,
                              hipStream_t stream) {
    const float* x    = (const float*)d_in[0];
    const float* wgt  = (const float*)d_in[1];
    const int*   dil  = (const int*)d_in[2];
    const int*   step = (const int*)d_in[3];
    float*       out  = (float*)d_out;

    const int B = in_sizes[0] / (CIN * H * W);
    const int total = B * H * OSPLIT * TPR;      // one thread per 4 w's per o-half
    const int block = 256;
    const int grid  = (total + block - 1) / block;

    skel_conv_kernel<<<grid, block, 0, stream>>>(x, wgt, dil, step, out, B);
}

// Round 3
// 161.410 us; speedup vs baseline: 16.1846x; 16.1846x over previous
//
#include <hip/hip_runtime.h>

// SkeletonConv: out[b,o,h,w] = sum_{c,k} W[o,c,k] * x[b,c, h+(k-1)*step, w+(k-1)*dil]
// B=64, C_in=C_out=16, K=3, H=W=256, fp32.
// R3: o-split x2 (8 outs/thread, 32 acc VGPRs), branchless depth-1 prefetch over c,
//     NO min-wave launch_bounds (R2's (256,8) caused catastrophic spill: 9GB scratch),
//     #pragma unroll 1 on c-loop to keep register pressure flat, NT output stores.

constexpr int CIN = 16, COUT = 16, KK = 3, H = 256, W = 256;
constexpr int WT  = 4;            // w-elements per thread (float4)
constexpr int TPR = W / WT;       // 64 threads = one wave per (b,h,half) row
constexpr int OSPLIT = 2, OPT = COUT / OSPLIT;   // 8 output channels per thread

typedef float f4 __attribute__((ext_vector_type(4)));

__global__ __launch_bounds__(256)
void skel_conv_kernel(const float* __restrict__ x, const float* __restrict__ wgt,
                      const int* __restrict__ dil_p, const int* __restrict__ step_p,
                      float* __restrict__ out, int B)
{
    const int dil  = dil_p[0];
    const int step = step_p[0];

    const int tid  = blockIdx.x * blockDim.x + threadIdx.x;
    const int lane = tid & (TPR - 1);            // lane-in-wave; wave spans a row
    int idx = tid / TPR;                         // (b, h, half)
    const int half = idx & (OSPLIT - 1);         // both halves of a row in one block -> L1 reuse
    idx >>= 1;
    const int h = idx & (H - 1);
    const int b = idx >> 8;
    if (b >= B) return;
    const int w0    = lane * WT;
    const int obase = half * OPT;

    float acc[OPT][WT];
    #pragma unroll
    for (int o = 0; o < OPT; ++o)
        #pragma unroll
        for (int j = 0; j < WT; ++j) acc[o][j] = 0.f;

    const size_t cs = (size_t)H * W;
    const float* xr = x + (size_t)b * CIN * cs + (size_t)h * W + w0;

    if (dil == 1 && step == 0) {
        // Fast path: horizontal 3-tap conv, depth-1 software pipeline over c.
        f4 v = *(const f4*)xr;                   // c = 0
        #pragma unroll 1
        for (int c = 0; c < CIN; ++c) {
            // branchless prefetch: last iter re-reads current row (L1 hit, discarded)
            const size_t noff = (c + 1 < CIN) ? (size_t)(c + 1) * cs : (size_t)c * cs;
            f4 vn = *(const f4*)(xr + noff);

            float left  = __shfl_up(v.w, 1);     // x[w0-1]
            float right = __shfl_down(v.x, 1);   // x[w0+4]
            if (lane == 0)       left  = 0.f;    // zero padding
            if (lane == TPR - 1) right = 0.f;

            #pragma unroll
            for (int oo = 0; oo < OPT; ++oo) {
                const float* wp = wgt + ((size_t)(obase + oo) * CIN + c) * KK;
                const float a0 = wp[0], a1 = wp[1], a2 = wp[2];   // uniform -> s_load
                acc[oo][0] += a0 * left + a1 * v.x + a2 * v.y;
                acc[oo][1] += a0 * v.x  + a1 * v.y + a2 * v.z;
                acc[oo][2] += a0 * v.y  + a1 * v.z + a2 * v.w;
                acc[oo][3] += a0 * v.z  + a1 * v.w + a2 * right;
            }
            v = vn;
        }
    } else {
        // Generic path: clamped loads + select (never faults, any dil/step).
        #pragma unroll 1
        for (int c = 0; c < CIN; ++c) {
            const float* xc = x + (size_t)b * CIN * cs + (size_t)c * cs;
            #pragma unroll
            for (int k = 0; k < KK; ++k) {
                const int off = k - KK / 2;
                const int hh  = h + off * step;
                const bool rowok = (hh >= 0) && (hh < H);
                const int hcl = hh < 0 ? 0 : (hh > H - 1 ? H - 1 : hh);
                float t[WT];
                #pragma unroll
                for (int j = 0; j < WT; ++j) {
                    const int ww  = w0 + j + off * dil;
                    const bool ok = rowok && (ww >= 0) && (ww < W);
                    const int wcl = ww < 0 ? 0 : (ww > W - 1 ? W - 1 : ww);
                    const float vv = xc[(size_t)hcl * W + wcl];
                    t[j] = ok ? vv : 0.f;
                }
                #pragma unroll
                for (int oo = 0; oo < OPT; ++oo) {
                    const float wk = wgt[((size_t)(obase + oo) * CIN + c) * KK + k];
                    #pragma unroll
                    for (int j = 0; j < WT; ++j)
                        acc[oo][j] += wk * t[j];
                }
            }
        }
    }

    float* orow = out + ((size_t)b * COUT + obase) * cs + (size_t)h * W + w0;
    #pragma unroll
    for (int oo = 0; oo < OPT; ++oo) {
        f4 r = {acc[oo][0], acc[oo][1], acc[oo][2], acc[oo][3]};
        __builtin_nontemporal_store(r, (f4*)(orow + (size_t)oo * cs));  // keep x in L3
    }
}

extern "C" void kernel_launch(void* const* d_in, const int* in_sizes, int n_in,
                              void* d_out, int out_size, void* d_ws, size_t ws_size,
                              hipStream_t stream) {
    const float* x    = (const float*)d_in[0];
    const float* wgt  = (const float*)d_in[1];
    const int*   dil  = (const int*)d_in[2];
    const int*   step = (const int*)d_in[3];
    float*       out  = (float*)d_out;

    const int B = in_sizes[0] / (CIN * H * W);
    const int total = B * H * OSPLIT * TPR;      // one thread per 4 w's per o-half
    const int block = 256;
    const int grid  = (total + block - 1) / block;

    skel_conv_kernel<<<grid, block, 0, stream>>>(x, wgt, dil, step, out, B);
}